// Round 19
// baseline (410.980 us; speedup 1.0000x reference)
//
#include <hip/hip_runtime.h>
#include <hip/hip_bf16.h>
#include <stdint.h>

typedef __bf16 bf16x8 __attribute__((ext_vector_type(8)));
typedef float  f32x4  __attribute__((ext_vector_type(4)));

#define DEV __device__ __forceinline__

constexpr int SUBJ  = 4;
constexpr int IN    = 4096;
constexpr int H     = 2048;
constexpr int DEPTH = 6;
constexpr int BATCH = 1024;
constexpr int BOT   = 128;
constexpr int IMG   = 768;
constexpr int TXT   = 768;
constexpr int MP    = 1408;   // padded sorted rows
constexpr int MT    = 11;     // MP/128 row tiles

DEV float gelu_exact(float x){ return 0.5f*x*(1.0f + erff(x*0.70710678118654752440f)); }

DEV uint16_t bf16_bits(float x){
  __hip_bfloat16 h = __float2bfloat16(x);
  return *reinterpret_cast<uint16_t*>(&h);
}
DEV float bfu(uint32_t w, int hi){
  uint32_t x = hi ? (w & 0xffff0000u) : (w << 16);
  return __uint_as_float(x);
}
DEV float bf2f(uint16_t u){ uint32_t x = (uint32_t)u << 16; return __uint_as_float(x); }

// 16-element one-shot fp32->bf16 convert (measured-best shape, cached loads)
DEV void cvt16(const float* __restrict__ s, __hip_bfloat16* __restrict__ d){
  float4 a = *reinterpret_cast<const float4*>(s);
  float4 b = *reinterpret_cast<const float4*>(s + 4);
  float4 c = *reinterpret_cast<const float4*>(s + 8);
  float4 e = *reinterpret_cast<const float4*>(s + 12);
  uint16_t o[16] = {bf16_bits(a.x), bf16_bits(a.y), bf16_bits(a.z), bf16_bits(a.w),
                    bf16_bits(b.x), bf16_bits(b.y), bf16_bits(b.z), bf16_bits(b.w),
                    bf16_bits(c.x), bf16_bits(c.y), bf16_bits(c.z), bf16_bits(c.w),
                    bf16_bits(e.x), bf16_bits(e.y), bf16_bits(e.z), bf16_bits(e.w)};
  *reinterpret_cast<uint4*>(d)     = *reinterpret_cast<const uint4*>(&o[0]);
  *reinterpret_cast<uint4*>(d + 8) = *reinterpret_cast<const uint4*>(&o[8]);
}

// standalone convert (upfront small segments: w_down, w_up)
__global__ void convert_plain(const float* __restrict__ src, __hip_bfloat16* __restrict__ dst,
                              size_t items){
  size_t it = (size_t)blockIdx.x*blockDim.x + threadIdx.x;
  if (it >= items) return;
  cvt16(src + (it<<4), dst + (it<<4));
}

// ---------------- subject counting-sort (1 block, 1024 threads) ----------------
__global__ void sort_kernel(const int* __restrict__ ids, int* __restrict__ rowmap,
                            int* __restrict__ tileS){
  __shared__ int hist[16][4];
  __shared__ int basew[16][4];
  __shared__ int pstart[5];
  int tid = threadIdx.x;
  if (tid < MP) rowmap[tid] = -1;
  if (tid + 1024 < MP) rowmap[tid + 1024] = -1;
  int w = tid >> 6, lane = tid & 63;
  int my = ids[tid];
  unsigned long long mymask = 0ull;
  #pragma unroll
  for (int s = 0; s < 4; ++s){
    unsigned long long m = __ballot(my == s);
    if (lane == 0) hist[w][s] = (int)__popcll(m);
    if (s == my) mymask = m;
  }
  int myrank = (int)__popcll(mymask & ((1ull << lane) - 1ull));
  __syncthreads();
  if (tid == 0){
    for (int s = 0; s < 4; ++s){
      int run = 0;
      for (int ww = 0; ww < 16; ++ww){ basew[ww][s] = run; run += hist[ww][s]; }
      hist[0][s] = run;
    }
    pstart[0] = 0;
    for (int s = 0; s < 4; ++s) pstart[s+1] = pstart[s] + ((hist[0][s] + 127) & ~127);
  }
  __syncthreads();
  int pos = pstart[my] + basew[w][my] + myrank;
  rowmap[pos] = tid;
  if (tid < MT){
    int row0 = tid << 7, s = -1;
    for (int ss = 0; ss < 4; ++ss) if (row0 >= pstart[ss] && row0 < pstart[ss+1]) s = ss;
    tileS[tid] = s;
  }
}

// ---------------- gather voxels into sorted order, fp32 -> bf16 ----------------
__global__ void gather_voxels(const float* __restrict__ vox, const int* __restrict__ rowmap,
                              __hip_bfloat16* __restrict__ Vs){
  int r = blockIdx.x, tid = threadIdx.x;
  int orig = rowmap[r];
  #pragma unroll
  for (int i = 0; i < 4; ++i){
    int c = (i*256 + tid) << 2;
    float4 v = {0.f,0.f,0.f,0.f};
    if (orig >= 0) v = *reinterpret_cast<const float4*>(vox + (size_t)orig*IN + c);
    __hip_bfloat16 o[4] = {__float2bfloat16(v.x), __float2bfloat16(v.y),
                           __float2bfloat16(v.z), __float2bfloat16(v.w)};
    *reinterpret_cast<uint2*>(Vs + (size_t)r*IN + c) = *reinterpret_cast<const uint2*>(o);
  }
}

// ---------------- 128x128 tile MFMA GEMM + co-resident cvt tail blocks --------------
// Blocks with blockIdx >= ggrid convert weights for a FUTURE dispatch, using HBM BW
// the latency-bound GEMM blocks leave idle. Stream order guarantees completion
// before the consumer dispatch launches.
enum { EPI_SPLIT = 0, EPI_RES_BF16 = 1, EPI_HEADS = 3 };

template<int EPI, int TAG>
__global__ __launch_bounds__(256, 2)
void gemm_bf16(const __hip_bfloat16* __restrict__ A, int lda,
               const __hip_bfloat16* __restrict__ Bw, int ldn, long long wsub,
               const int* __restrict__ tileS, const int* __restrict__ rowmap,
               int nx, int qnt, int ksplit,
               const float* __restrict__ bias, int biassub,
               const float* __restrict__ resid, int ldres,
               __hip_bfloat16* __restrict__ outb, int ldo,
               size_t pstride, const __hip_bfloat16* __restrict__ Bw2,
               int ggrid, const float* __restrict__ csrc,
               __hip_bfloat16* __restrict__ cdst, size_t citems)
{
  int b = blockIdx.x;
  if (b >= ggrid){                          // cvt tail block
    size_t it = (size_t)(b - ggrid)*blockDim.x + threadIdx.x;
    if (it < citems) cvt16(csrc + (it<<4), cdst + (it<<4));
    return;
  }
  int xcd = b & 7;
  int r0  = b >> 3;
  int mt  = r0 % MT;
  int q   = r0 / MT;
  int kzi = xcd / nx + (q / qnt) * (8 / nx);
  int nt  = (q % qnt) * nx + (xcd % nx);

  int s = tileS[mt];
  if (s < 0) return;                       // inactive (pad) row tile
  const __hip_bfloat16* Ab = A + (size_t)mt*128*lda;

  const __hip_bfloat16* Bb;
  int ntl = nt;
  if constexpr (EPI == EPI_HEADS){
    if (nt < 6){ Bb = Bw  + (size_t)nt*128; }
    else       { Bb = Bw2 + (size_t)(nt-6)*128; }
    ntl = nt;                              // col in concat [0,1536)
  } else {
    Bb = Bw + (size_t)s*wsub + (size_t)nt*128;
  }

  int kb = kzi * ksplit;
  int nk = ksplit >> 6;

  __shared__ __hip_bfloat16 sA[2][128*64];
  __shared__ __hip_bfloat16 sB[2][128*64];

  int tid = threadIdx.x;
  int lane = tid & 63;
  int wv = tid >> 6, wr = wv >> 1, wc = wv & 1;

  int kq = tid >> 5;                       // 0..7: k-chunk of 8 rows
  int nq = tid & 31;                       // n-col group of 4
  int n4 = nq << 2;

  f32x4 acc[4][4];
  #pragma unroll
  for (int i = 0; i < 4; ++i)
    #pragma unroll
    for (int j = 0; j < 4; ++j) acc[i][j] = (f32x4){0.f,0.f,0.f,0.f};

  auto stageA = [&](int buf, int k0){
    #pragma unroll
    for (int i = 0; i < 4; ++i){
      int cell = i*256 + tid;
      int row = cell >> 3, cc = cell & 7;
      int kg = k0 + ((cc ^ (row & 7)) << 3);
      __builtin_amdgcn_global_load_lds(
        (const __attribute__((address_space(1))) void*)(Ab + (size_t)row*lda + kg),
        (__attribute__((address_space(3))) void*)(&sA[buf][cell<<3]), 16, 0, 0);
    }
  };

  auto stageB_load = [&](int k0g, uint2* F){
    const __hip_bfloat16* p = Bb + (size_t)(k0g + (kq<<3))*ldn + n4;
    #pragma unroll
    for (int rr = 0; rr < 8; ++rr)
      F[rr] = *reinterpret_cast<const uint2*>(p + (size_t)rr*ldn);
  };
  auto stageB_write = [&](int buf, const uint2* F){
    #pragma unroll
    for (int j = 0; j < 4; ++j){
      int n = n4 + j;
      int cell = (kq ^ (n >> 3) ^ n) & 7;
      auto US = [&](int rr)->uint32_t{
        return (((const uint32_t*)&F[rr])[j >> 1] >> ((j & 1) * 16)) & 0xffffu;
      };
      uint4 d;
      d.x = US(0) | (US(1) << 16);
      d.y = US(2) | (US(3) << 16);
      d.z = US(4) | (US(5) << 16);
      d.w = US(6) | (US(7) << 16);
      *reinterpret_cast<uint4*>(&sB[buf][(n<<6) + (cell<<3)]) = d;
    }
  };

  uint2 F[8];
  stageB_load(kb, F);
  stageA(0, kb);
  stageB_write(0, F);
  __syncthreads();

  for (int t = 0; t < nk; ++t){
    if (t+1 < nk){
      stageB_load(kb + ((t+1)<<6), F);
      stageA((t+1)&1, kb + ((t+1)<<6));
    }
    const char* baseA = (const char*)(&sA[t&1][0]);
    const char* baseB = (const char*)(&sB[t&1][0]);
    int rA = (wr<<6) + (lane & 15);
    int rB = (wc<<6) + (lane & 15);
    #pragma unroll
    for (int kk = 0; kk < 2; ++kk){
      int koffA = ((((kk<<5) + ((lane>>4)<<3)) << 1)) ^ ((lane & 7) << 4);
      bf16x8 av[4], bv[4];
      #pragma unroll
      for (int f = 0; f < 4; ++f){
        int rowA = rA + f*16;
        av[f] = *reinterpret_cast<const bf16x8*>(baseA + (size_t)rowA*128 + koffA);
        int rowB = rB + f*16;
        int cellB = (((kk<<2) + (lane>>4)) ^ (rowB >> 3) ^ rowB) & 7;
        bv[f] = *reinterpret_cast<const bf16x8*>(baseB + (size_t)rowB*128 + (cellB<<4));
      }
      #pragma unroll
      for (int i = 0; i < 4; ++i)
        #pragma unroll
        for (int j = 0; j < 4; ++j)
          acc[i][j] = __builtin_amdgcn_mfma_f32_16x16x32_bf16(av[i], bv[j], acc[i][j], 0, 0, 0);
    }
    if (t+1 < nk) stageB_write((t+1)&1, F);
    __syncthreads();
  }

  // epilogue; C/D layout (m89-verified): col = lane&15, row = (lane>>4)*4 + reg
  #pragma unroll
  for (int i = 0; i < 4; ++i){
    int rbase = (mt<<7) + (wr<<6) + (i<<4) + ((lane>>4)<<2);
    #pragma unroll
    for (int j = 0; j < 4; ++j){
      int colp = (wc<<6) + (j<<4) + (lane & 15);
      #pragma unroll
      for (int qq = 0; qq < 4; ++qq){
        int r = rbase + qq;
        float v = acc[i][j][qq];
        if constexpr (EPI == EPI_SPLIT){
          int col = (nt<<7) + colp;
          outb[(size_t)kzi*pstride + (size_t)r*ldo + col] = __float2bfloat16(v);
        } else if constexpr (EPI == EPI_RES_BF16){
          int col = (nt<<7) + colp;
          int orig = rowmap[r];
          if (orig >= 0){
            v += bias[(size_t)s*biassub + col] + resid[(size_t)orig*ldres + col];
            outb[(size_t)r*ldo + col] = __float2bfloat16(v);
          }
        } else { // EPI_HEADS: bf16 partial (concat col space)
          int col = (ntl<<7) + colp;
          outb[(size_t)kzi*pstride + (size_t)r*ldo + col] = __float2bfloat16(v);
        }
      }
    }
  }
}

// ---------------- T1 = gelu(sum_p T1p + db[s])  (bf16 partials) ----------------
template<int NPART>
__global__ void t1_epilogue(const __hip_bfloat16* __restrict__ Tp, const float* __restrict__ db,
                            const int* __restrict__ rowmap, const int* __restrict__ tileS,
                            __hip_bfloat16* __restrict__ T1){
  int idx = blockIdx.x*256 + threadIdx.x;
  int r = idx >> 7, c = idx & 127;
  float v = 0.f;
  if (rowmap[r] >= 0){
    int s = tileS[r >> 7];
    float acc = 0.f;
    #pragma unroll
    for (int p = 0; p < NPART; ++p)
      acc += bf2f(*reinterpret_cast<const uint16_t*>(Tp + (size_t)p*MP*BOT + idx));
    v = gelu_exact(acc + db[s*BOT + c]);
  }
  T1[idx] = __float2bfloat16(v);
}

// ------- row LN over summed bf16 partials (+linear bias) + gelu (+bf16 residual) ------
template<int RES, int NPART>
__global__ void ln_gelu_kernel(const __hip_bfloat16* __restrict__ Zp, size_t pstride,
                               const float* __restrict__ g,
                               const float* __restrict__ b, int gsub,
                               const float* __restrict__ lb,
                               const int* __restrict__ tileS, const int* __restrict__ rowmap,
                               __hip_bfloat16* __restrict__ Xb){
  int r = blockIdx.x, tid = threadIdx.x;
  size_t rowoff = (size_t)r * H;
  int c0 = tid << 3;
  int orig = rowmap[r];
  if (orig < 0){
    uint4 zu = {0u,0u,0u,0u};
    *reinterpret_cast<uint4*>(Xb + rowoff + c0) = zu;
    return;
  }
  int si = gsub ? tileS[r>>7] : 0;
  const float* gp  = g  + (size_t)si*gsub;
  const float* bp  = b  + (size_t)si*gsub;
  const float* lbp = lb + (size_t)si*gsub;
  float z[8];
  #pragma unroll
  for (int j = 0; j < 8; ++j) z[j] = lbp[c0+j];
  #pragma unroll
  for (int p = 0; p < NPART; ++p){
    uint4 v = *reinterpret_cast<const uint4*>(Zp + p*pstride + rowoff + c0);
    z[0] += bfu(v.x,0); z[1] += bfu(v.x,1);
    z[2] += bfu(v.y,0); z[3] += bfu(v.y,1);
    z[4] += bfu(v.z,0); z[5] += bfu(v.z,1);
    z[6] += bfu(v.w,0); z[7] += bfu(v.w,1);
  }
  float s1 = 0.f, s2 = 0.f;
  #pragma unroll
  for (int j = 0; j < 8; ++j){ s1 += z[j]; s2 += z[j]*z[j]; }
  #pragma unroll
  for (int m = 32; m >= 1; m >>= 1){ s1 += __shfl_xor(s1, m); s2 += __shfl_xor(s2, m); }
  __shared__ float red[4][2];
  int wv = tid >> 6, lane = tid & 63;
  if (lane == 0){ red[wv][0] = s1; red[wv][1] = s2; }
  __syncthreads();
  s1 = red[0][0]+red[1][0]+red[2][0]+red[3][0];
  s2 = red[0][1]+red[1][1]+red[2][1]+red[3][1];
  const float invH = 1.f / (float)H;
  float mu  = s1 * invH;
  float var = s2 * invH - mu*mu;
  float rs  = rsqrtf(var + 1e-5f);
  float o[8];
  #pragma unroll
  for (int j = 0; j < 8; ++j){
    float t = (z[j]-mu)*rs*gp[c0+j] + bp[c0+j];
    o[j] = gelu_exact(t);
  }
  if constexpr (RES){
    uint4 xv = *reinterpret_cast<const uint4*>(Xb + rowoff + c0);
    o[0] += bfu(xv.x,0); o[1] += bfu(xv.x,1);
    o[2] += bfu(xv.y,0); o[3] += bfu(xv.y,1);
    o[4] += bfu(xv.z,0); o[5] += bfu(xv.z,1);
    o[6] += bfu(xv.w,0); o[7] += bfu(xv.w,1);
  }
  __hip_bfloat16 ob[8];
  #pragma unroll
  for (int j = 0; j < 8; ++j) ob[j] = __float2bfloat16(o[j]);
  *reinterpret_cast<uint4*>(Xb + rowoff + c0) = *reinterpret_cast<const uint4*>(ob);
}

// ---------------- heads combine: sum NPART bf16 partials + bias, scatter ---------------
template<int NPART>
__global__ void head_combine(const __hip_bfloat16* __restrict__ Hp, size_t pstride,
                             const float* __restrict__ img_b, const float* __restrict__ txt_b,
                             const int* __restrict__ rowmap,
                             float* __restrict__ oimg, float* __restrict__ otxt){
  int r = blockIdx.x;
  int orig = rowmap[r];
  if (orig < 0) return;
  int col = threadIdx.x << 2;                    // 384 threads x 4 cols = 1536
  size_t base = (size_t)r*(IMG+TXT) + col;
  float4 acc = {0.f,0.f,0.f,0.f};
  #pragma unroll
  for (int p = 0; p < NPART; ++p){
    uint2 u = *reinterpret_cast<const uint2*>(Hp + (size_t)p*pstride + base);
    acc.x += bfu(u.x,0); acc.y += bfu(u.x,1);
    acc.z += bfu(u.y,0); acc.w += bfu(u.y,1);
  }
  float4 bb = (col < IMG)
            ? *reinterpret_cast<const float4*>(img_b + col)
            : *reinterpret_cast<const float4*>(txt_b + (col - IMG));
  float4 o = {acc.x+bb.x, acc.y+bb.y, acc.z+bb.z, acc.w+bb.w};
  if (col < IMG) *reinterpret_cast<float4*>(oimg + (size_t)orig*IMG + col) = o;
  else           *reinterpret_cast<float4*>(otxt + (size_t)orig*TXT + (col-IMG)) = o;
}

// ------------------------------------------------------------------------------
extern "C" void kernel_launch(void* const* d_in, const int* in_sizes, int n_in,
                              void* d_out, int out_size, void* d_ws, size_t ws_size,
                              hipStream_t stream){
  (void)in_sizes; (void)n_in; (void)out_size; (void)ws_size;
  const float* vox       = (const float*)d_in[0];
  const int*   ids       = (const int*)  d_in[1];
  const float* ad_down_w = (const float*)d_in[2];
  const float* ad_down_b = (const float*)d_in[3];
  const float* ad_up_w   = (const float*)d_in[4];
  const float* ad_up_b   = (const float*)d_in[5];
  const float* enc_w     = (const float*)d_in[6];
  const float* enc_b     = (const float*)d_in[7];
  const float* enc_ln_g  = (const float*)d_in[8];
  const float* enc_ln_bb = (const float*)d_in[9];
  const float* bb_w      = (const float*)d_in[10];
  const float* bb_b      = (const float*)d_in[11];
  const float* bb_ln_g   = (const float*)d_in[12];
  const float* bb_ln_b   = (const float*)d_in[13];
  const float* img_w     = (const float*)d_in[14];
  const float* img_b     = (const float*)d_in[15];
  const float* txt_w     = (const float*)d_in[16];
  const float* txt_b     = (const float*)d_in[17];
  float* out = (float*)d_out;

  // bf16 weight pool segment sizes (elements)
  const size_t N_DOWN = (size_t)SUBJ*IN*BOT;
  const size_t N_UP   = (size_t)SUBJ*BOT*IN;
  const size_t N_ENC  = (size_t)SUBJ*IN*H;
  const size_t N_BB   = (size_t)DEPTH*H*H;
  const size_t N_IMG  = (size_t)H*IMG;
  const size_t N_TXT  = (size_t)H*TXT;

  char* wp = (char*)d_ws;
  auto alloc = [&](size_t bytes)->char*{ char* p = wp; wp += (bytes + 255) & ~(size_t)255; return p; };
  int* rowmap = (int*)alloc(MP * sizeof(int));
  int* tileS  = (int*)alloc(MT * sizeof(int));
  __hip_bfloat16* Wbf = (__hip_bfloat16*)alloc((N_DOWN+N_UP+N_ENC+N_BB+N_IMG+N_TXT)*2);
  __hip_bfloat16* w_down = Wbf;
  __hip_bfloat16* w_up   = w_down + N_DOWN;
  __hip_bfloat16* w_enc  = w_up   + N_UP;
  __hip_bfloat16* w_bb   = w_enc  + N_ENC;
  __hip_bfloat16* w_img  = w_bb   + N_BB;
  __hip_bfloat16* w_txt  = w_img  + N_IMG;
  __hip_bfloat16* Vs    = (__hip_bfloat16*)alloc((size_t)MP*IN*2);
  __hip_bfloat16* T1p   = (__hip_bfloat16*)alloc((size_t)32*MP*BOT*2);
  __hip_bfloat16* T1    = (__hip_bfloat16*)alloc((size_t)MP*BOT*2);
  __hip_bfloat16* Hs    = (__hip_bfloat16*)alloc((size_t)MP*IN*2);
  __hip_bfloat16* Zp    = (__hip_bfloat16*)alloc((size_t)4*MP*H*2);
  __hip_bfloat16* Hp    = Zp;               // alias: Zp dead before heads GEMM writes Hp
  __hip_bfloat16* Xb    = (__hip_bfloat16*)alloc((size_t)MP*H*2);

  const size_t ZPS = (size_t)MP*H;
  const size_t TPS = (size_t)MP*BOT;
  const size_t HPS = (size_t)MP*(IMG+TXT);

  // item counts for cvt (16 elem/item)
  const size_t I_DOWN = N_DOWN >> 4, I_UP = N_UP >> 4, I_ENC = N_ENC >> 4;
  const size_t I_BB = N_BB >> 4, I_IMG = N_IMG >> 4, I_TXT = N_TXT >> 4;
  const size_t I_ENC_H = I_ENC >> 1;        // half of w_enc per carrier dispatch
  auto nb = [](size_t items){ return (int)((items + 255) / 256); };

  // upfront: the two small adapter weights (w_down needed by K1, w_up by K2)
  convert_plain<<<nb(I_DOWN), 256, 0, stream>>>(ad_down_w, w_down, I_DOWN);
  convert_plain<<<nb(I_UP),   256, 0, stream>>>(ad_up_w,   w_up,   I_UP);

  sort_kernel<<<1, 1024, 0, stream>>>(ids, rowmap, tileS);
  gather_voxels<<<MP, 256, 0, stream>>>(vox, rowmap, Vs);

  // K1 + cvt(w_enc first half): NT=1, KZ=32 (nx=1, qnt=1, ksplit=128), ggrid 352.
  gemm_bf16<EPI_SPLIT,1><<<MT*32 + nb(I_ENC_H), 256, 0, stream>>>(
      Vs, IN, w_down, BOT, (long long)IN*BOT, tileS, rowmap, 1, 1, 128,
      nullptr, 0, nullptr, 0, T1p, BOT, TPS, nullptr,
      MT*32, enc_w, w_enc, I_ENC_H);
  t1_epilogue<32><<<MP*BOT/256, 256, 0, stream>>>(T1p, ad_down_b, rowmap, tileS, T1);

  // K2 + cvt(w_enc second half): NT=32, KZ=1 (nx=8, qnt=4, ksplit=128), ggrid 352.
  gemm_bf16<EPI_RES_BF16,2><<<MT*32 + nb(I_ENC - I_ENC_H), 256, 0, stream>>>(
      T1, BOT, w_up, IN, (long long)BOT*IN, tileS, rowmap, 8, 4, 128,
      ad_up_b, IN, vox, IN, Hs, IN, 0, nullptr,
      MT*32, enc_w + (I_ENC_H<<4), w_enc + (I_ENC_H<<4), I_ENC - I_ENC_H);

  // K3 + cvt(w_bb): NT=16, KZ=4 (nx=2, qnt=8, ksplit=1024), ggrid 704.
  gemm_bf16<EPI_SPLIT,3><<<MT*8*8 + nb(I_BB), 256, 0, stream>>>(
      Hs, IN, w_enc, H, (long long)IN*H, tileS, rowmap, 2, 8, 1024,
      nullptr, 0, nullptr, 0, Zp, H, ZPS, nullptr,
      MT*8*8, bb_w, w_bb, I_BB);
  ln_gelu_kernel<0,4><<<MP, 256, 0, stream>>>(Zp, ZPS, enc_ln_g, enc_ln_bb, H, enc_b,
                                              tileS, rowmap, Xb);

  // backbone: layer 0 rides cvt(w_img), layer 1 rides cvt(w_txt).
  for (int d = 0; d < DEPTH; ++d){
    const float* cs = (d == 0) ? img_w : (d == 1) ? txt_w : nullptr;
    __hip_bfloat16* cd = (d == 0) ? w_img : (d == 1) ? w_txt : nullptr;
    size_t ci = (d == 0) ? I_IMG : (d == 1) ? I_TXT : 0;
    int tail = (d <= 1) ? nb(ci) : 0;
    gemm_bf16<EPI_SPLIT,4><<<MT*4*8 + tail, 256, 0, stream>>>(
        Xb, H, w_bb + (size_t)d*H*H, H, 0, tileS, rowmap, 4, 4, 1024,
        nullptr, 0, nullptr, 0, Zp, H, ZPS, nullptr,
        MT*4*8, cs, cd, ci);
    ln_gelu_kernel<1,2><<<MP, 256, 0, stream>>>(Zp, ZPS, bb_ln_g + (size_t)d*H,
                                                bb_ln_b + (size_t)d*H, 0, bb_b + (size_t)d*H,
                                                tileS, rowmap, Xb);
  }

  // heads: ONE gemm, NT=12, KZ=2 (nx=4, qnt=3, ksplit=1024), grid 264, no tail.
  gemm_bf16<EPI_HEADS,5><<<MT*3*8, 256, 0, stream>>>(
      Xb, H, w_img, IMG, 0, tileS, rowmap, 4, 3, 1024,
      nullptr, 0, nullptr, 0, Hp, IMG+TXT, HPS, w_txt,
      MT*3*8, nullptr, nullptr, 0);
  head_combine<2><<<MP, 384, 0, stream>>>(Hp, HPS, img_b, txt_b, rowmap,
                                          out, out + (size_t)BATCH*IMG);
}

// Round 20
// 401.955 us; speedup vs baseline: 1.0225x; 1.0225x over previous
//
#include <hip/hip_runtime.h>
#include <hip/hip_bf16.h>
#include <stdint.h>

typedef __bf16 bf16x8 __attribute__((ext_vector_type(8)));
typedef float  f32x4  __attribute__((ext_vector_type(4)));

#define DEV __device__ __forceinline__

constexpr int SUBJ  = 4;
constexpr int IN    = 4096;
constexpr int H     = 2048;
constexpr int DEPTH = 6;
constexpr int BATCH = 1024;
constexpr int BOT   = 128;
constexpr int IMG   = 768;
constexpr int TXT   = 768;
constexpr int MP    = 1408;   // padded sorted rows
constexpr int MT    = 11;     // MP/128 row tiles

DEV float gelu_exact(float x){ return 0.5f*x*(1.0f + erff(x*0.70710678118654752440f)); }

DEV uint16_t bf16_bits(float x){
  __hip_bfloat16 h = __float2bfloat16(x);
  return *reinterpret_cast<uint16_t*>(&h);
}
DEV float bfu(uint32_t w, int hi){
  uint32_t x = hi ? (w & 0xffff0000u) : (w << 16);
  return __uint_as_float(x);
}
DEV float bf2f(uint16_t u){ uint32_t x = (uint32_t)u << 16; return __uint_as_float(x); }

// 16-element one-shot fp32->bf16 convert (measured-best shape, cached loads)
DEV void cvt16(const float* __restrict__ s, __hip_bfloat16* __restrict__ d){
  float4 a = *reinterpret_cast<const float4*>(s);
  float4 b = *reinterpret_cast<const float4*>(s + 4);
  float4 c = *reinterpret_cast<const float4*>(s + 8);
  float4 e = *reinterpret_cast<const float4*>(s + 12);
  uint16_t o[16] = {bf16_bits(a.x), bf16_bits(a.y), bf16_bits(a.z), bf16_bits(a.w),
                    bf16_bits(b.x), bf16_bits(b.y), bf16_bits(b.z), bf16_bits(b.w),
                    bf16_bits(c.x), bf16_bits(c.y), bf16_bits(c.z), bf16_bits(c.w),
                    bf16_bits(e.x), bf16_bits(e.y), bf16_bits(e.z), bf16_bits(e.w)};
  *reinterpret_cast<uint4*>(d)     = *reinterpret_cast<const uint4*>(&o[0]);
  *reinterpret_cast<uint4*>(d + 8) = *reinterpret_cast<const uint4*>(&o[8]);
}

// standalone convert (used only for the small upfront w_down segment)
__global__ void convert_plain(const float* __restrict__ src, __hip_bfloat16* __restrict__ dst,
                              size_t items){
  size_t it = (size_t)blockIdx.x*blockDim.x + threadIdx.x;
  if (it >= items) return;
  cvt16(src + (it<<4), dst + (it<<4));
}

// ---------------- subject counting-sort (1 block, 1024 threads) ----------------
__global__ void sort_kernel(const int* __restrict__ ids, int* __restrict__ rowmap,
                            int* __restrict__ tileS){
  __shared__ int hist[16][4];
  __shared__ int basew[16][4];
  __shared__ int pstart[5];
  int tid = threadIdx.x;
  if (tid < MP) rowmap[tid] = -1;
  if (tid + 1024 < MP) rowmap[tid + 1024] = -1;
  int w = tid >> 6, lane = tid & 63;
  int my = ids[tid];
  unsigned long long mymask = 0ull;
  #pragma unroll
  for (int s = 0; s < 4; ++s){
    unsigned long long m = __ballot(my == s);
    if (lane == 0) hist[w][s] = (int)__popcll(m);
    if (s == my) mymask = m;
  }
  int myrank = (int)__popcll(mymask & ((1ull << lane) - 1ull));
  __syncthreads();
  if (tid == 0){
    for (int s = 0; s < 4; ++s){
      int run = 0;
      for (int ww = 0; ww < 16; ++ww){ basew[ww][s] = run; run += hist[ww][s]; }
      hist[0][s] = run;
    }
    pstart[0] = 0;
    for (int s = 0; s < 4; ++s) pstart[s+1] = pstart[s] + ((hist[0][s] + 127) & ~127);
  }
  __syncthreads();
  int pos = pstart[my] + basew[w][my] + myrank;
  rowmap[pos] = tid;
  if (tid < MT){
    int row0 = tid << 7, s = -1;
    for (int ss = 0; ss < 4; ++ss) if (row0 >= pstart[ss] && row0 < pstart[ss+1]) s = ss;
    tileS[tid] = s;
  }
}

// ---------------- gather voxels into sorted order, fp32 -> bf16 ----------------
__global__ void gather_voxels(const float* __restrict__ vox, const int* __restrict__ rowmap,
                              __hip_bfloat16* __restrict__ Vs){
  int r = blockIdx.x, tid = threadIdx.x;
  int orig = rowmap[r];
  #pragma unroll
  for (int i = 0; i < 4; ++i){
    int c = (i*256 + tid) << 2;
    float4 v = {0.f,0.f,0.f,0.f};
    if (orig >= 0) v = *reinterpret_cast<const float4*>(vox + (size_t)orig*IN + c);
    __hip_bfloat16 o[4] = {__float2bfloat16(v.x), __float2bfloat16(v.y),
                           __float2bfloat16(v.z), __float2bfloat16(v.w)};
    *reinterpret_cast<uint2*>(Vs + (size_t)r*IN + c) = *reinterpret_cast<const uint2*>(o);
  }
}

// ---------------- 128x128 tile MFMA GEMM + co-resident cvt tail blocks --------------
// Blocks with blockIdx >= ggrid convert weights for a FUTURE dispatch, using the HBM
// bandwidth the latency-bound GEMM blocks leave idle. Stream order guarantees the
// conversion completes before its consumer dispatch launches.
// GEMM decode: xcd=b&7; r=b>>3; mt=r%MT; q=r/MT;
//              kzi = xcd/nx + (q/qnt)*(8/nx);  nt = (q%qnt)*nx + xcd%nx.
enum { EPI_SPLIT = 0, EPI_RES_BF16 = 1, EPI_HEADS = 3 };

template<int EPI, int TAG>
__global__ __launch_bounds__(256, 2)
void gemm_bf16(const __hip_bfloat16* __restrict__ A, int lda,
               const __hip_bfloat16* __restrict__ Bw, int ldn, long long wsub,
               const int* __restrict__ tileS, const int* __restrict__ rowmap,
               int nx, int qnt, int ksplit,
               const float* __restrict__ bias, int biassub,
               const float* __restrict__ resid, int ldres,
               __hip_bfloat16* __restrict__ outb, int ldo,
               size_t pstride, const __hip_bfloat16* __restrict__ Bw2,
               int ggrid, const float* __restrict__ csrc,
               __hip_bfloat16* __restrict__ cdst, size_t citems)
{
  int b = blockIdx.x;
  if (b >= ggrid){                          // cvt tail block
    size_t it = (size_t)(b - ggrid)*blockDim.x + threadIdx.x;
    if (it < citems) cvt16(csrc + (it<<4), cdst + (it<<4));
    return;
  }
  int xcd = b & 7;
  int r0  = b >> 3;
  int mt  = r0 % MT;
  int q   = r0 / MT;
  int kzi = xcd / nx + (q / qnt) * (8 / nx);
  int nt  = (q % qnt) * nx + (xcd % nx);

  int s = tileS[mt];
  if (s < 0) return;                       // inactive (pad) row tile
  const __hip_bfloat16* Ab = A + (size_t)mt*128*lda;

  const __hip_bfloat16* Bb;
  int ntl = nt;
  if constexpr (EPI == EPI_HEADS){
    if (nt < 6){ Bb = Bw  + (size_t)nt*128; }
    else       { Bb = Bw2 + (size_t)(nt-6)*128; }
    ntl = nt;                              // col in concat [0,1536)
  } else {
    Bb = Bw + (size_t)s*wsub + (size_t)nt*128;
  }

  int kb = kzi * ksplit;
  int nk = ksplit >> 6;

  __shared__ __hip_bfloat16 sA[2][128*64];
  __shared__ __hip_bfloat16 sB[2][128*64];

  int tid = threadIdx.x;
  int lane = tid & 63;
  int wv = tid >> 6, wr = wv >> 1, wc = wv & 1;

  int kq = tid >> 5;                       // 0..7: k-chunk of 8 rows
  int nq = tid & 31;                       // n-col group of 4
  int n4 = nq << 2;

  f32x4 acc[4][4];
  #pragma unroll
  for (int i = 0; i < 4; ++i)
    #pragma unroll
    for (int j = 0; j < 4; ++j) acc[i][j] = (f32x4){0.f,0.f,0.f,0.f};

  auto stageA = [&](int buf, int k0){
    #pragma unroll
    for (int i = 0; i < 4; ++i){
      int cell = i*256 + tid;
      int row = cell >> 3, cc = cell & 7;
      int kg = k0 + ((cc ^ (row & 7)) << 3);
      __builtin_amdgcn_global_load_lds(
        (const __attribute__((address_space(1))) void*)(Ab + (size_t)row*lda + kg),
        (__attribute__((address_space(3))) void*)(&sA[buf][cell<<3]), 16, 0, 0);
    }
  };

  auto stageB_load = [&](int k0g, uint2* F){
    const __hip_bfloat16* p = Bb + (size_t)(k0g + (kq<<3))*ldn + n4;
    #pragma unroll
    for (int rr = 0; rr < 8; ++rr)
      F[rr] = *reinterpret_cast<const uint2*>(p + (size_t)rr*ldn);
  };
  auto stageB_write = [&](int buf, const uint2* F){
    #pragma unroll
    for (int j = 0; j < 4; ++j){
      int n = n4 + j;
      int cell = (kq ^ (n >> 3) ^ n) & 7;
      auto US = [&](int rr)->uint32_t{
        return (((const uint32_t*)&F[rr])[j >> 1] >> ((j & 1) * 16)) & 0xffffu;
      };
      uint4 d;
      d.x = US(0) | (US(1) << 16);
      d.y = US(2) | (US(3) << 16);
      d.z = US(4) | (US(5) << 16);
      d.w = US(6) | (US(7) << 16);
      *reinterpret_cast<uint4*>(&sB[buf][(n<<6) + (cell<<3)]) = d;
    }
  };

  uint2 F[8];
  stageB_load(kb, F);
  stageA(0, kb);
  stageB_write(0, F);
  __syncthreads();

  for (int t = 0; t < nk; ++t){
    if (t+1 < nk){
      stageB_load(kb + ((t+1)<<6), F);
      stageA((t+1)&1, kb + ((t+1)<<6));
    }
    const char* baseA = (const char*)(&sA[t&1][0]);
    const char* baseB = (const char*)(&sB[t&1][0]);
    int rA = (wr<<6) + (lane & 15);
    int rB = (wc<<6) + (lane & 15);
    #pragma unroll
    for (int kk = 0; kk < 2; ++kk){
      int koffA = ((((kk<<5) + ((lane>>4)<<3)) << 1)) ^ ((lane & 7) << 4);
      bf16x8 av[4], bv[4];
      #pragma unroll
      for (int f = 0; f < 4; ++f){
        int rowA = rA + f*16;
        av[f] = *reinterpret_cast<const bf16x8*>(baseA + (size_t)rowA*128 + koffA);
        int rowB = rB + f*16;
        int cellB = (((kk<<2) + (lane>>4)) ^ (rowB >> 3) ^ rowB) & 7;
        bv[f] = *reinterpret_cast<const bf16x8*>(baseB + (size_t)rowB*128 + (cellB<<4));
      }
      #pragma unroll
      for (int i = 0; i < 4; ++i)
        #pragma unroll
        for (int j = 0; j < 4; ++j)
          acc[i][j] = __builtin_amdgcn_mfma_f32_16x16x32_bf16(av[i], bv[j], acc[i][j], 0, 0, 0);
    }
    if (t+1 < nk) stageB_write((t+1)&1, F);
    __syncthreads();
  }

  // epilogue; C/D layout (m89-verified): col = lane&15, row = (lane>>4)*4 + reg
  #pragma unroll
  for (int i = 0; i < 4; ++i){
    int rbase = (mt<<7) + (wr<<6) + (i<<4) + ((lane>>4)<<2);
    #pragma unroll
    for (int j = 0; j < 4; ++j){
      int colp = (wc<<6) + (j<<4) + (lane & 15);
      #pragma unroll
      for (int qq = 0; qq < 4; ++qq){
        int r = rbase + qq;
        float v = acc[i][j][qq];
        if constexpr (EPI == EPI_SPLIT){
          int col = (nt<<7) + colp;
          outb[(size_t)kzi*pstride + (size_t)r*ldo + col] = __float2bfloat16(v);
        } else if constexpr (EPI == EPI_RES_BF16){
          int col = (nt<<7) + colp;
          int orig = rowmap[r];
          if (orig >= 0){
            v += bias[(size_t)s*biassub + col] + resid[(size_t)orig*ldres + col];
            outb[(size_t)r*ldo + col] = __float2bfloat16(v);
          }
        } else { // EPI_HEADS: bf16 partial (concat col space)
          int col = (ntl<<7) + colp;
          outb[(size_t)kzi*pstride + (size_t)r*ldo + col] = __float2bfloat16(v);
        }
      }
    }
  }
}

// ---------------- T1 = gelu(sum_p T1p + db[s])  (bf16 partials) ----------------
template<int NPART>
__global__ void t1_epilogue(const __hip_bfloat16* __restrict__ Tp, const float* __restrict__ db,
                            const int* __restrict__ rowmap, const int* __restrict__ tileS,
                            __hip_bfloat16* __restrict__ T1){
  int idx = blockIdx.x*256 + threadIdx.x;
  int r = idx >> 7, c = idx & 127;
  float v = 0.f;
  if (rowmap[r] >= 0){
    int s = tileS[r >> 7];
    float acc = 0.f;
    #pragma unroll
    for (int p = 0; p < NPART; ++p)
      acc += bf2f(*reinterpret_cast<const uint16_t*>(Tp + (size_t)p*MP*BOT + idx));
    v = gelu_exact(acc + db[s*BOT + c]);
  }
  T1[idx] = __float2bfloat16(v);
}

// ------- row LN over summed bf16 partials (+linear bias) + gelu (+bf16 residual) ------
template<int RES, int NPART>
__global__ void ln_gelu_kernel(const __hip_bfloat16* __restrict__ Zp, size_t pstride,
                               const float* __restrict__ g,
                               const float* __restrict__ b, int gsub,
                               const float* __restrict__ lb,
                               const int* __restrict__ tileS, const int* __restrict__ rowmap,
                               __hip_bfloat16* __restrict__ Xb){
  int r = blockIdx.x, tid = threadIdx.x;
  size_t rowoff = (size_t)r * H;
  int c0 = tid << 3;
  int orig = rowmap[r];
  if (orig < 0){
    uint4 zu = {0u,0u,0u,0u};
    *reinterpret_cast<uint4*>(Xb + rowoff + c0) = zu;
    return;
  }
  int si = gsub ? tileS[r>>7] : 0;
  const float* gp  = g  + (size_t)si*gsub;
  const float* bp  = b  + (size_t)si*gsub;
  const float* lbp = lb + (size_t)si*gsub;
  float z[8];
  #pragma unroll
  for (int j = 0; j < 8; ++j) z[j] = lbp[c0+j];
  #pragma unroll
  for (int p = 0; p < NPART; ++p){
    uint4 v = *reinterpret_cast<const uint4*>(Zp + p*pstride + rowoff + c0);
    z[0] += bfu(v.x,0); z[1] += bfu(v.x,1);
    z[2] += bfu(v.y,0); z[3] += bfu(v.y,1);
    z[4] += bfu(v.z,0); z[5] += bfu(v.z,1);
    z[6] += bfu(v.w,0); z[7] += bfu(v.w,1);
  }
  float s1 = 0.f, s2 = 0.f;
  #pragma unroll
  for (int j = 0; j < 8; ++j){ s1 += z[j]; s2 += z[j]*z[j]; }
  #pragma unroll
  for (int m = 32; m >= 1; m >>= 1){ s1 += __shfl_xor(s1, m); s2 += __shfl_xor(s2, m); }
  __shared__ float red[4][2];
  int wv = tid >> 6, lane = tid & 63;
  if (lane == 0){ red[wv][0] = s1; red[wv][1] = s2; }
  __syncthreads();
  s1 = red[0][0]+red[1][0]+red[2][0]+red[3][0];
  s2 = red[0][1]+red[1][1]+red[2][1]+red[3][1];
  const float invH = 1.f / (float)H;
  float mu  = s1 * invH;
  float var = s2 * invH - mu*mu;
  float rs  = rsqrtf(var + 1e-5f);
  float o[8];
  #pragma unroll
  for (int j = 0; j < 8; ++j){
    float t = (z[j]-mu)*rs*gp[c0+j] + bp[c0+j];
    o[j] = gelu_exact(t);
  }
  if constexpr (RES){
    uint4 xv = *reinterpret_cast<const uint4*>(Xb + rowoff + c0);
    o[0] += bfu(xv.x,0); o[1] += bfu(xv.x,1);
    o[2] += bfu(xv.y,0); o[3] += bfu(xv.y,1);
    o[4] += bfu(xv.z,0); o[5] += bfu(xv.z,1);
    o[6] += bfu(xv.w,0); o[7] += bfu(xv.w,1);
  }
  __hip_bfloat16 ob[8];
  #pragma unroll
  for (int j = 0; j < 8; ++j) ob[j] = __float2bfloat16(o[j]);
  *reinterpret_cast<uint4*>(Xb + rowoff + c0) = *reinterpret_cast<const uint4*>(ob);
}

// ---------------- heads combine: sum NPART bf16 partials + bias, scatter ---------------
template<int NPART>
__global__ void head_combine(const __hip_bfloat16* __restrict__ Hp, size_t pstride,
                             const float* __restrict__ img_b, const float* __restrict__ txt_b,
                             const int* __restrict__ rowmap,
                             float* __restrict__ oimg, float* __restrict__ otxt){
  int r = blockIdx.x;
  int orig = rowmap[r];
  if (orig < 0) return;
  int col = threadIdx.x << 2;                    // 384 threads x 4 cols = 1536
  size_t base = (size_t)r*(IMG+TXT) + col;
  float4 acc = {0.f,0.f,0.f,0.f};
  #pragma unroll
  for (int p = 0; p < NPART; ++p){
    uint2 u = *reinterpret_cast<const uint2*>(Hp + (size_t)p*pstride + base);
    acc.x += bfu(u.x,0); acc.y += bfu(u.x,1);
    acc.z += bfu(u.y,0); acc.w += bfu(u.y,1);
  }
  float4 bb = (col < IMG)
            ? *reinterpret_cast<const float4*>(img_b + col)
            : *reinterpret_cast<const float4*>(txt_b + (col - IMG));
  float4 o = {acc.x+bb.x, acc.y+bb.y, acc.z+bb.z, acc.w+bb.w};
  if (col < IMG) *reinterpret_cast<float4*>(oimg + (size_t)orig*IMG + col) = o;
  else           *reinterpret_cast<float4*>(otxt + (size_t)orig*TXT + (col-IMG)) = o;
}

// ------------------------------------------------------------------------------
extern "C" void kernel_launch(void* const* d_in, const int* in_sizes, int n_in,
                              void* d_out, int out_size, void* d_ws, size_t ws_size,
                              hipStream_t stream){
  (void)in_sizes; (void)n_in; (void)out_size; (void)ws_size;
  const float* vox       = (const float*)d_in[0];
  const int*   ids       = (const int*)  d_in[1];
  const float* ad_down_w = (const float*)d_in[2];
  const float* ad_down_b = (const float*)d_in[3];
  const float* ad_up_w   = (const float*)d_in[4];
  const float* ad_up_b   = (const float*)d_in[5];
  const float* enc_w     = (const float*)d_in[6];
  const float* enc_b     = (const float*)d_in[7];
  const float* enc_ln_g  = (const float*)d_in[8];
  const float* enc_ln_bb = (const float*)d_in[9];
  const float* bb_w      = (const float*)d_in[10];
  const float* bb_b      = (const float*)d_in[11];
  const float* bb_ln_g   = (const float*)d_in[12];
  const float* bb_ln_b   = (const float*)d_in[13];
  const float* img_w     = (const float*)d_in[14];
  const float* img_b     = (const float*)d_in[15];
  const float* txt_w     = (const float*)d_in[16];
  const float* txt_b     = (const float*)d_in[17];
  float* out = (float*)d_out;

  // bf16 weight pool segment sizes (elements)
  const size_t N_DOWN = (size_t)SUBJ*IN*BOT;
  const size_t N_UP   = (size_t)SUBJ*BOT*IN;
  const size_t N_ENC  = (size_t)SUBJ*IN*H;
  const size_t N_BB   = (size_t)DEPTH*H*H;
  const size_t N_IMG  = (size_t)H*IMG;
  const size_t N_TXT  = (size_t)H*TXT;

  char* wp = (char*)d_ws;
  auto alloc = [&](size_t bytes)->char*{ char* p = wp; wp += (bytes + 255) & ~(size_t)255; return p; };
  int* rowmap = (int*)alloc(MP * sizeof(int));
  int* tileS  = (int*)alloc(MT * sizeof(int));
  __hip_bfloat16* Wbf = (__hip_bfloat16*)alloc((N_DOWN+N_UP+N_ENC+N_BB+N_IMG+N_TXT)*2);
  __hip_bfloat16* w_down = Wbf;
  __hip_bfloat16* w_up   = w_down + N_DOWN;
  __hip_bfloat16* w_enc  = w_up   + N_UP;
  __hip_bfloat16* w_bb   = w_enc  + N_ENC;
  __hip_bfloat16* w_img  = w_bb   + N_BB;
  __hip_bfloat16* w_txt  = w_img  + N_IMG;
  __hip_bfloat16* Vs    = (__hip_bfloat16*)alloc((size_t)MP*IN*2);
  __hip_bfloat16* T1p   = (__hip_bfloat16*)alloc((size_t)32*MP*BOT*2);
  __hip_bfloat16* T1    = (__hip_bfloat16*)alloc((size_t)MP*BOT*2);
  __hip_bfloat16* Hs    = (__hip_bfloat16*)alloc((size_t)MP*IN*2);
  __hip_bfloat16* Zp    = (__hip_bfloat16*)alloc((size_t)4*MP*H*2);
  __hip_bfloat16* Hp    = Zp;               // alias: Zp dead before heads GEMM writes Hp
  __hip_bfloat16* Xb    = (__hip_bfloat16*)alloc((size_t)MP*H*2);

  const size_t ZPS = (size_t)MP*H;
  const size_t TPS = (size_t)MP*BOT;
  const size_t HPS = (size_t)MP*(IMG+TXT);

  // item counts for cvt tails (16 elem/item)
  const size_t I_DOWN = N_DOWN >> 4, I_UP = N_UP >> 4, I_ENC = N_ENC >> 4;
  const size_t I_BB = N_BB >> 4, I_IMG = N_IMG >> 4, I_TXT = N_TXT >> 4;
  auto nb = [](size_t items){ return (int)((items + 255) / 256); };

  // upfront: only w_down (K1's weight). Everything else rides later dispatches.
  convert_plain<<<nb(I_DOWN), 256, 0, stream>>>(ad_down_w, w_down, I_DOWN);

  sort_kernel<<<1, 1024, 0, stream>>>(ids, rowmap, tileS);
  gather_voxels<<<MP, 256, 0, stream>>>(vox, rowmap, Vs);

  // K1 + cvt(w_up): NT=1, KZ=32 (nx=1, qnt=1, ksplit=128), ggrid 352.
  gemm_bf16<EPI_SPLIT,1><<<MT*32 + nb(I_UP), 256, 0, stream>>>(
      Vs, IN, w_down, BOT, (long long)IN*BOT, tileS, rowmap, 1, 1, 128,
      nullptr, 0, nullptr, 0, T1p, BOT, TPS, nullptr,
      MT*32, ad_up_w, w_up, I_UP);
  t1_epilogue<32><<<MP*BOT/256, 256, 0, stream>>>(T1p, ad_down_b, rowmap, tileS, T1);

  // K2 + cvt(w_enc): NT=32, KZ=1 (nx=8, qnt=4, ksplit=128), ggrid 352.
  gemm_bf16<EPI_RES_BF16,2><<<MT*32 + nb(I_ENC), 256, 0, stream>>>(
      T1, BOT, w_up, IN, (long long)BOT*IN, tileS, rowmap, 8, 4, 128,
      ad_up_b, IN, vox, IN, Hs, IN, 0, nullptr,
      MT*32, enc_w, w_enc, I_ENC);

  // K3 + cvt(w_bb): NT=16, KZ=4 (nx=2, qnt=8, ksplit=1024), ggrid 704.
  gemm_bf16<EPI_SPLIT,3><<<MT*8*8 + nb(I_BB), 256, 0, stream>>>(
      Hs, IN, w_enc, H, (long long)IN*H, tileS, rowmap, 2, 8, 1024,
      nullptr, 0, nullptr, 0, Zp, H, ZPS, nullptr,
      MT*8*8, bb_w, w_bb, I_BB);
  ln_gelu_kernel<0,4><<<MP, 256, 0, stream>>>(Zp, ZPS, enc_ln_g, enc_ln_bb, H, enc_b,
                                              tileS, rowmap, Xb);

  // backbone: layer 0 rides cvt(w_img), layer 1 rides cvt(w_txt).
  for (int d = 0; d < DEPTH; ++d){
    const float* cs = (d == 0) ? img_w : (d == 1) ? txt_w : nullptr;
    __hip_bfloat16* cd = (d == 0) ? w_img : (d == 1) ? w_txt : nullptr;
    size_t ci = (d == 0) ? I_IMG : (d == 1) ? I_TXT : 0;
    int tail = (d <= 1) ? nb(ci) : 0;
    gemm_bf16<EPI_SPLIT,4><<<MT*4*8 + tail, 256, 0, stream>>>(
        Xb, H, w_bb + (size_t)d*H*H, H, 0, tileS, rowmap, 4, 4, 1024,
        nullptr, 0, nullptr, 0, Zp, H, ZPS, nullptr,
        MT*4*8, cs, cd, ci);
    ln_gelu_kernel<1,2><<<MP, 256, 0, stream>>>(Zp, ZPS, bb_ln_g + (size_t)d*H,
                                                bb_ln_b + (size_t)d*H, 0, bb_b + (size_t)d*H,
                                                tileS, rowmap, Xb);
  }

  // heads: ONE gemm, NT=12, KZ=2 (nx=4, qnt=3, ksplit=1024), grid 264, no tail.
  gemm_bf16<EPI_HEADS,5><<<MT*3*8, 256, 0, stream>>>(
      Xb, H, w_img, IMG, 0, tileS, rowmap, 4, 3, 1024,
      nullptr, 0, nullptr, 0, Hp, IMG+TXT, HPS, w_txt,
      MT*3*8, nullptr, nullptr, 0);
  head_combine<2><<<MP, 384, 0, stream>>>(Hp, HPS, img_b, txt_b, rowmap,
                                          out, out + (size_t)BATCH*IMG);
}